// Round 7
// baseline (167.480 us; speedup 1.0000x reference)
//
#include <hip/hip_runtime.h>

// BirthDeathIntervalLoss: 2 sets x [B=32,C=4,N=64] intervals, each gathers
// birth/death from pred[B,C,H=512,W=512], diff=(b-d)^2, weighted sum.
// Weights folded analytically: good interval (n < g_c): -0.0625/g_c,
// bad: +0.0625/(64-g_c); constant term 14.0 (verified absmax=0.0 in R4).
// GOOD_0={1,2,1,3} -> 0x3121, GOOD_1={1,0,2,1} -> 0x1201.
//
// R5 (resubmitted R7 after infra timeouts): R4 profile showed timed window
// = 2x 512MiB harness poison fills (~79us each @ 85% HBM peak) + ~4us of
// our two kernels. Only kernel-addressable cost left is the second
// dispatch + inter-kernel drain. Fuse to ONE dispatch via last-block-ticket:
//  - each block: release-store partial to d_ws, acq_rel atomicAdd on a
//    module-global ticket (lives in .bss, NOT poisoned d_ws; self-resets
//    to 0 each call -> graph-replay safe, no co-residency/spin needed).
//  - 256th arrival: acquire-load all 256 partials in the SAME summation
//    order as the old bd_final (bitwise-identical result), +14.0, store.
// Poison-safe: all 256 d_ws slots written before any read (ticket order).

#define H_ 512
#define W_ 512

__device__ int bd_ticket = 0;   // zero-init at module load; self-resetting

__global__ __launch_bounds__(64) void bd_fused_kernel(
    const float* __restrict__ pred,
    const int4* __restrict__ iv0,
    const int4* __restrict__ iv1,
    float* __restrict__ partials,
    float* __restrict__ out)
{
    const int tid = blockIdx.x * 64 + threadIdx.x;  // [0, 16384)
    const int s   = tid >> 13;        // set index: 8192 intervals per set
    const int idx = tid & 8191;       // (b*C + c)*N + n
    const int n   = idx & 63;
    const int bc  = idx >> 6;         // b*C + c  in [0, 128)
    const int c   = bc & 3;

    // interval = {birth_row, birth_col, death_row, death_col}, 16B aligned
    const int4 iv = (s == 0 ? iv0 : iv1)[idx];

    const float birth = pred[(bc * H_ + iv.x) * W_ + iv.y];
    const float death = pred[(bc * H_ + iv.z) * W_ + iv.w];
    const float d = birth - death;
    const float diff = d * d;

    // good-interval counts packed as nibbles: set0 {1,2,1,3}, set1 {1,0,2,1}
    const int packed = (s == 0) ? 0x3121 : 0x1201;
    const int g = (packed >> (c << 2)) & 0xF;

    // g==0 => n >= g always => bad path only (no div-by-zero)
    const float w = (n < g) ? (-0.0625f / (float)g)
                            : ( 0.0625f / (float)(64 - g));
    float v = w * diff;

    // wave-64 shuffle reduction (whole block is one wave)
    #pragma unroll
    for (int off = 32; off > 0; off >>= 1)
        v += __shfl_down(v, off, 64);

    int rank = 0;
    if (threadIdx.x == 0) {
        // release: partial visible device-wide before ticket increments
        __hip_atomic_store(&partials[blockIdx.x], v,
                           __ATOMIC_RELEASE, __HIP_MEMORY_SCOPE_AGENT);
        rank = __hip_atomic_fetch_add(&bd_ticket, 1,
                                      __ATOMIC_ACQ_REL, __HIP_MEMORY_SCOPE_AGENT);
    }
    rank = __shfl(rank, 0, 64);

    if (rank == 255) {
        // last-arriving block: all 256 partials are globally visible.
        // Same summation order as old bd_final float4 path:
        // lane reads partials[4*lane .. 4*lane+3], (a+b)+(c+d), shfl chain.
        const int base = threadIdx.x * 4;
        const float p0 = __hip_atomic_load(&partials[base + 0],
                             __ATOMIC_ACQUIRE, __HIP_MEMORY_SCOPE_AGENT);
        const float p1 = __hip_atomic_load(&partials[base + 1],
                             __ATOMIC_ACQUIRE, __HIP_MEMORY_SCOPE_AGENT);
        const float p2 = __hip_atomic_load(&partials[base + 2],
                             __ATOMIC_ACQUIRE, __HIP_MEMORY_SCOPE_AGENT);
        const float p3 = __hip_atomic_load(&partials[base + 3],
                             __ATOMIC_ACQUIRE, __HIP_MEMORY_SCOPE_AGENT);
        float t = (p0 + p1) + (p2 + p3);
        #pragma unroll
        for (int off = 32; off > 0; off >>= 1)
            t += __shfl_down(t, off, 64);
        if (threadIdx.x == 0) {
            out[0] = t + 14.0f;   // analytic constant term
            bd_ticket = 0;        // reset for next call (kernel-end fence)
        }
    }
}

extern "C" void kernel_launch(void* const* d_in, const int* in_sizes, int n_in,
                              void* d_out, int out_size, void* d_ws, size_t ws_size,
                              hipStream_t stream) {
    const float* pred = (const float*)d_in[0];
    const int4*  iv0  = (const int4*)d_in[1];
    const int4*  iv1  = (const int4*)d_in[2];
    float* partials = (float*)d_ws;   // 256 floats, all overwritten each call
    float* out = (float*)d_out;

    // 2 * 32 * 4 * 64 = 16384 intervals, one thread each, one wave per block
    bd_fused_kernel<<<256, 64, 0, stream>>>(pred, iv0, iv1, partials, out);
}

// Round 8
// 162.749 us; speedup vs baseline: 1.0291x; 1.0291x over previous
//
#include <hip/hip_runtime.h>

// BirthDeathIntervalLoss: 2 sets x [B=32,C=4,N=64] intervals, each gathers
// birth/death from pred[B,C,H=512,W=512], diff=(b-d)^2, weighted sum.
// Weights folded analytically: good interval (n < g_c): -0.0625/g_c,
// bad: +0.0625/(64-g_c); constant term 14.0 (verified absmax=0.0, R4+R7).
// GOOD_0={1,2,1,3} -> 0x3121, GOOD_1={1,0,2,1} -> 0x1201.
//
// R8: REVERT to the R4 two-kernel form (best measured: 162.8us).
// R7 post-mortem: single-dispatch ticket fusion measured 167.5us (+4.7).
// Under graph replay the 2nd dispatch is nearly free, while the fused
// form pays per-block agent-scope release/acq_rel cache ops + runs the
// final reduce in the last block's tail. Fusion rejected on measurement.
//
// Timed window is ~97% harness poison fills (2 x 512MiB @ 84-86% HBM
// peak ~= 158us); kernel share ~5us, near the 2-chained-cold-miss
// latency floor. This structure is the roofline candidate.
//
// Structure: 256 blocks x 64 threads (one wave per block) so all 256 CUs
// share the scattered-gather miss handling; no LDS, no __syncthreads.
// Two-stage reduction, NO memset: kernel1 overwrites d_ws[0..255] with
// per-wave partials (poison-safe: every slot written unconditionally),
// kernel2 (one wave, float4/lane) reduces 256 partials + 14.0 into d_out.

#define H_ 512
#define W_ 512

__global__ __launch_bounds__(64) void bd_partial_kernel(
    const float* __restrict__ pred,
    const int4* __restrict__ iv0,
    const int4* __restrict__ iv1,
    float* __restrict__ partials)
{
    const int tid = blockIdx.x * 64 + threadIdx.x;  // [0, 16384)
    const int s   = tid >> 13;        // set index: 8192 intervals per set
    const int idx = tid & 8191;       // (b*C + c)*N + n
    const int n   = idx & 63;
    const int bc  = idx >> 6;         // b*C + c  in [0, 128)
    const int c   = bc & 3;

    // interval = {birth_row, birth_col, death_row, death_col}, 16B aligned
    const int4 iv = (s == 0 ? iv0 : iv1)[idx];

    const float birth = pred[(bc * H_ + iv.x) * W_ + iv.y];
    const float death = pred[(bc * H_ + iv.z) * W_ + iv.w];
    const float d = birth - death;
    const float diff = d * d;

    // good-interval counts packed as nibbles: set0 {1,2,1,3}, set1 {1,0,2,1}
    const int packed = (s == 0) ? 0x3121 : 0x1201;
    const int g = (packed >> (c << 2)) & 0xF;

    // g==0 => n >= g always => bad path only (no div-by-zero)
    const float w = (n < g) ? (-0.0625f / (float)g)
                            : ( 0.0625f / (float)(64 - g));
    float v = w * diff;

    // wave-64 shuffle reduction (whole block is one wave)
    #pragma unroll
    for (int off = 32; off > 0; off >>= 1)
        v += __shfl_down(v, off, 64);

    if (threadIdx.x == 0) partials[blockIdx.x] = v;
}

__global__ __launch_bounds__(64) void bd_final_kernel(
    const float4* __restrict__ partials,
    float* __restrict__ out)
{
    const float4 p = partials[threadIdx.x];   // 256 partials = 64 lanes x 4
    float v = (p.x + p.y) + (p.z + p.w);
    #pragma unroll
    for (int off = 32; off > 0; off >>= 1)
        v += __shfl_down(v, off, 64);
    if (threadIdx.x == 0) out[0] = v + 14.0f;  // analytic constant term
}

extern "C" void kernel_launch(void* const* d_in, const int* in_sizes, int n_in,
                              void* d_out, int out_size, void* d_ws, size_t ws_size,
                              hipStream_t stream) {
    const float* pred = (const float*)d_in[0];
    const int4*  iv0  = (const int4*)d_in[1];
    const int4*  iv1  = (const int4*)d_in[2];
    float* partials = (float*)d_ws;   // 256 floats, all overwritten each call
    float* out = (float*)d_out;

    // 2 * 32 * 4 * 64 = 16384 intervals, one thread each, one wave per block
    bd_partial_kernel<<<256, 64, 0, stream>>>(pred, iv0, iv1, partials);
    bd_final_kernel<<<1, 64, 0, stream>>>((const float4*)partials, out);
}